// Round 12
// baseline (232.011 us; speedup 1.0000x reference)
//
#include <hip/hip_runtime.h>

#define M_ 16
#define H_ 32
#define D_ 128
#define P_ 8192
#define N_ 4096
#define PM_ 8208   // P + M

// workspace layout (float offsets) — no region needs pre-zeroing
#define WS_Q    0          // [32][16][128] q
#define WS_K    65536      // [32][16][128] new k
#define WS_V    131072     // [32][16][128] new v
#define WS_S1   196608     // [512]
#define WS_S2   197120     // [512]
#define WS_IS2  197632     // [512] 1/s2
#define WS_XQ   198144     // x_norm as float4 [1024][16]
#define WS_E2   263680     // e2t [32][8208][16] (h,p,m)  (ends 4,466,176)
#define WS_E1   4466176    // e1t [32][8208][16] (h,p,m)  (ends 8,668,672)
#define WS_PP   263680     // proj partials [32][16][12288] — ALIASES E2+E1 head (dead before qk)
#define WS_PO   8668672    // pv O partials [32][32][16][128] (ends 10,765,824)
#define WS_SP1  10765824   // [32*32][16] s1 per block (ends 10,782,208)
#define WS_SP2  10782208   // [32*32][16]              (ends 10,798,592)
// total = 10,798,592 floats = 43.2 MB

// ---------------- Kernel A: RMS norm ----------------
__global__ __launch_bounds__(256) void rmsnorm_kernel(const float* __restrict__ X,
                                                      float* __restrict__ ws) {
  int m = blockIdx.x, t = threadIdx.x;
  __shared__ float red[256];
  const float4* X4 = (const float4*)(X + (size_t)m * N_);
  float s = 0.f;
  #pragma unroll
  for (int q = 0; q < 4; q++) {
    float4 v = X4[t + q * 256];
    s += v.x * v.x + v.y * v.y + v.z * v.z + v.w * v.w;
  }
  red[t] = s;
  __syncthreads();
  for (int off = 128; off > 0; off >>= 1) {
    if (t < off) red[t] += red[t + off];
    __syncthreads();
  }
  float scale = rsqrtf(red[0] * (1.0f / N_));
  float4* xq = (float4*)(ws + WS_XQ);
  #pragma unroll
  for (int q = 0; q < 4; q++) {
    int nq = t + q * 256;
    float4 v = X4[nq];
    v.x *= scale; v.y *= scale; v.z *= scale; v.w *= scale;
    xq[nq * 16 + m] = v;  // xq[n/4][m]
  }
}

// ---------------- Kernel B: QKV projection — per-lane row streaming ----------------
// No LDS, no staging, no races. Lane owns output column j = jj0+lane = W row j.
// Streams its own row in 64B bursts (4x dwordx4, full line consumed from regs).
// x reads are wave-uniform -> s_load (scalar pipe). Store-free alias-free loop
// -> compiler pipelines load batches deeply. k-split x32 for TLP (24 waves/CU).
__global__ __launch_bounds__(256, 4) void proj_kernel(const float* __restrict__ Wq,
                                                      const float* __restrict__ Wk,
                                                      const float* __restrict__ Wv,
                                                      const float* __restrict__ xr,
                                                      float* __restrict__ ws) {
  int widx = threadIdx.x >> 6, lane = threadIdx.x & 63;
  int kc = blockIdx.x / 48;                 // 0..31, block-uniform
  int jt = (blockIdx.x % 48) * 4 + widx;    // 0..191
  int jj0 = jt * 64;
  int sel = jj0 >> 12;                      // 0=q 1=k 2=v
  int j0 = jj0 & 4095;
  const float* Wm = (sel == 0) ? Wq : ((sel == 1) ? Wk : Wv);
  int n0 = kc * 128;                        // 32 quads per kc

  const float4* wrow = (const float4*)(Wm + (size_t)(j0 + lane) * N_ + n0);
  const float4* xr4 = (const float4*)xr;

  float acc[16];
  #pragma unroll
  for (int m = 0; m < 16; m++) acc[m] = 0.f;

  #pragma unroll
  for (int g = 0; g < 8; g++) {            // 8 groups x 4 quads = 64B bursts
    float4 w4[4];
    #pragma unroll
    for (int i = 0; i < 4; i++) w4[i] = wrow[g * 4 + i];
    #pragma unroll
    for (int i = 0; i < 4; i++) {
      int qbase = ((n0 >> 2) + g * 4 + i) * 16;
      #pragma unroll
      for (int m = 0; m < 16; m++) {
        float4 xm = xr4[qbase + m];        // uniform -> s_load
        acc[m] += xm.x * w4[i].x + xm.y * w4[i].y + xm.z * w4[i].z + xm.w * w4[i].w;
      }
    }
  }

  // partial store: PP[kc][m][jj0+lane], coalesced 256B per m
  float* pp = ws + WS_PP + (size_t)kc * 16 * 12288 + jj0 + lane;
  #pragma unroll
  for (int m = 0; m < 16; m++) pp[(size_t)m * 12288] = acc[m];
}

// ---------------- Kernel B2: reduce proj partials over kc ----------------
__global__ __launch_bounds__(256) void proj_reduce_kernel(float* __restrict__ ws) {
  int tid = blockIdx.x * 256 + threadIdx.x;  // 0..196607
  int m = tid / 12288;
  int j = tid - m * 12288;
  float acc = 0.f;
  #pragma unroll
  for (int kc = 0; kc < 32; kc++)
    acc += ws[WS_PP + ((size_t)(kc * 16 + m)) * 12288 + j];
  int sel = j >> 12, jj = j & 4095;
  int h = jj >> 7, d = jj & 127;
  ws[WS_Q + sel * 65536 + (h * 16 + m) * 128 + d] = acc;
}

// ---------------- Kernel C1a: QK^T + softmax numerators (R10 proven) ----------------
__global__ __launch_bounds__(256) void qk_kernel(const float* __restrict__ cacheK,
                                                 const float* __restrict__ noise,
                                                 const float* __restrict__ taup,
                                                 float* __restrict__ ws) {
  __shared__ float sred[2][4][16];
  int h = blockIdx.x >> 5, b = blockIdx.x & 31;
  int widx = threadIdx.x >> 6, lane = threadIdx.x & 63;
  int m8 = lane & 7, sl = lane >> 3;
  int rsel = lane >> 4;
  int msel = lane & 15;
  bool tb = (lane >> 3) & 1;
  bool rb0 = rsel & 1, rb1 = (rsel >> 1) & 1;
  bool hb = sl >> 2, sb0 = sl & 1, sb1 = (sl >> 1) & 1;
  float inv_tau = 1.0f / taup[0];

  float qv[2][16];
  #pragma unroll
  for (int t = 0; t < 2; t++) {
    const float4* qp = (const float4*)(ws + WS_Q + ((size_t)(h * 16) + m8 + 8 * t) * 128 + sl * 16);
    #pragma unroll
    for (int jq = 0; jq < 4; jq++) {
      float4 v = qp[jq];
      qv[t][jq * 4] = v.x; qv[t][jq * 4 + 1] = v.y;
      qv[t][jq * 4 + 2] = v.z; qv[t][jq * 4 + 3] = v.w;
    }
  }
  float s1 = 0.f, s2 = 0.f;

  const float* nbase = noise + ((size_t)h * 16 + msel) * PM_;
  float* e2base = ws + WS_E2 + (size_t)h * PM_ * 16 + msel;
  float* e1base = ws + WS_E1 + (size_t)h * PM_ * 16 + (sl & 3) * 16 + (sl >> 2) * 8 + m8;
  const float* kc_base = cacheK + (size_t)h * P_ * D_;

  auto qk_one = [&](int p0, const float* kb) {
    float nz = nbase[p0 + rsel];

    float pr[4][2];
    #pragma unroll
    for (int r = 0; r < 4; r++) {
      float4 kq[4];
      const float4* krp = (const float4*)(kb + r * D_ + sl * 16);
      kq[0] = krp[0]; kq[1] = krp[1]; kq[2] = krp[2]; kq[3] = krp[3];
      const float* kk = (const float*)kq;
      float t0 = 0.f, t1 = 0.f;
      #pragma unroll
      for (int j = 0; j < 16; j++) { t0 += kk[j] * qv[0][j]; t1 += kk[j] * qv[1][j]; }
      pr[r][0] = t0; pr[r][1] = t1;
    }
    float cc[4][2];
    #pragma unroll
    for (int r = 0; r < 4; r++)
      #pragma unroll
      for (int t = 0; t < 2; t++) {
        float v = pr[r][t];
        v += __shfl_xor(v, 8, 64);
        v += __shfl_xor(v, 16, 64);
        v += __shfl_xor(v, 32, 64);
        cc[r][t] = v;
      }

    float a0 = tb ? cc[0][1] : cc[0][0];
    float a1 = tb ? cc[1][1] : cc[1][0];
    float a2 = tb ? cc[2][1] : cc[2][0];
    float a3 = tb ? cc[3][1] : cc[3][0];
    float b0 = rb0 ? a1 : a0;
    float b1 = rb0 ? a3 : a2;
    float myc = rb1 ? b1 : b0;
    float e2 = __expf((myc + nz) * inv_tau);
    e2base[(size_t)(p0 + rsel) * 16] = e2;
    s2 += e2;

    float e1[4][2];
    #pragma unroll
    for (int r = 0; r < 4; r++) {
      e1[r][0] = __expf(cc[r][0]);
      e1[r][1] = __expf(cc[r][1]);
    }
    float f0 = tb ? e1[0][1] : e1[0][0];
    float f1 = tb ? e1[1][1] : e1[1][0];
    float f2 = tb ? e1[2][1] : e1[2][0];
    float f3 = tb ? e1[3][1] : e1[3][0];
    float g0s = rb0 ? f1 : f0;
    float g1s = rb0 ? f3 : f2;
    s1 += rb1 ? g1s : g0s;

    float u0 = hb ? e1[0][1] : e1[0][0];
    float u1 = hb ? e1[1][1] : e1[1][0];
    float u2 = hb ? e1[2][1] : e1[2][0];
    float u3 = hb ? e1[3][1] : e1[3][0];
    float w0 = sb0 ? u1 : u0;
    float w1 = sb0 ? u3 : u2;
    float val = sb1 ? w1 : w0;
    e1base[(size_t)p0 * 16] = val;
  };

  int g0 = b * 64;
  for (int gl = widx; gl < 64; gl += 4) {
    int p0 = (g0 + gl) * 4;
    qk_one(p0, kc_base + (size_t)p0 * D_);
  }
  if (b == 31) {
    int p0 = P_ + widx * 4;
    qk_one(p0, ws + WS_K + ((size_t)h * 16 + widx * 4) * 128);
  }

  s1 += __shfl_xor(s1, 16, 64); s1 += __shfl_xor(s1, 32, 64);
  s2 += __shfl_xor(s2, 16, 64); s2 += __shfl_xor(s2, 32, 64);
  if (lane < 16) { sred[0][widx][lane] = s1; sred[1][widx][lane] = s2; }
  __syncthreads();
  if (threadIdx.x < 16) {
    int mm = threadIdx.x;
    float a  = sred[0][0][mm] + sred[0][1][mm] + sred[0][2][mm] + sred[0][3][mm];
    float c2 = sred[1][0][mm] + sred[1][1][mm] + sred[1][2][mm] + sred[1][3][mm];
    ws[WS_SP1 + (size_t)(h * 32 + b) * 16 + mm] = a;
    ws[WS_SP2 + (size_t)(h * 32 + b) * 16 + mm] = c2;
  }
}

// ---------------- Kernel C1b: PV accumulate (R10 proven) ----------------
__global__ __launch_bounds__(256) void pv_kernel(const float* __restrict__ cacheV,
                                                 const float* __restrict__ ws,
                                                 float* __restrict__ wout) {
  __shared__ float red[4 * 2048];
  int h = blockIdx.x >> 5, b = blockIdx.x & 31;
  int widx = threadIdx.x >> 6, lane = threadIdx.x & 63;
  int m8 = lane & 7, sl = lane >> 3;

  float oacc[2][16];
  #pragma unroll
  for (int t = 0; t < 2; t++)
    #pragma unroll
    for (int j = 0; j < 16; j++) oacc[t][j] = 0.f;

  const float* e1r = ws + WS_E1 + (size_t)h * PM_ * 16 + m8;
  const float* vc_base = cacheV + (size_t)h * P_ * D_;

  auto pv_one = [&](int p0, const float* vb) {
    float ea[4], eb[4];
    #pragma unroll
    for (int r = 0; r < 4; r++) {
      ea[r] = e1r[(size_t)p0 * 16 + r * 16];
      eb[r] = e1r[(size_t)p0 * 16 + r * 16 + 8];
    }
    #pragma unroll
    for (int r = 0; r < 4; r++) {
      float4 vq[4];
      const float4* vrp = (const float4*)(vb + r * D_ + sl * 16);
      vq[0] = vrp[0]; vq[1] = vrp[1]; vq[2] = vrp[2]; vq[3] = vrp[3];
      const float* vv = (const float*)vq;
      #pragma unroll
      for (int j = 0; j < 16; j++) {
        oacc[0][j] += ea[r] * vv[j];
        oacc[1][j] += eb[r] * vv[j];
      }
    }
  };

  int g0 = b * 64;
  for (int gl = widx; gl < 64; gl += 4) {
    int p0 = (g0 + gl) * 4;
    pv_one(p0, vc_base + (size_t)p0 * D_);
  }
  if (b == 31) {
    int p0 = P_ + widx * 4;
    pv_one(p0, ws + WS_V + ((size_t)h * 16 + widx * 4) * 128);
  }

  float* rw = red + widx * 2048 + lane * 32;
  #pragma unroll
  for (int t = 0; t < 2; t++)
    #pragma unroll
    for (int j = 0; j < 16; j++) {
      int i = t * 16 + j;
      rw[(i + lane) & 31] = oacc[t][j];
    }
  __syncthreads();

  float* po = wout + WS_PO + (size_t)(h * 32 + b) * 2048;
  for (int e = threadIdx.x; e < 2048; e += 256) {
    int ln = e >> 5, i = e & 31;
    int phys = (ln << 5) + ((i + ln) & 31);
    float v = red[phys] + red[phys + 2048] + red[phys + 4096] + red[phys + 6144];
    int mo = (ln & 7) + 8 * (i >> 4);
    int d = (ln >> 3) * 16 + (i & 15);
    po[mo * 128 + d] = v;
  }
}

// ---------------- Kernel S: final s1/s2 sums + 1/s2 ----------------
__global__ __launch_bounds__(256) void sums_kernel(float* __restrict__ ws) {
  int tid = blockIdx.x * 256 + threadIdx.x;
  if (tid >= 512) return;
  int h = tid >> 4, m = tid & 15;
  float a = 0.f, c2 = 0.f;
  #pragma unroll
  for (int b = 0; b < 32; b++) {
    a  += ws[WS_SP1 + (size_t)(h * 32 + b) * 16 + m];
    c2 += ws[WS_SP2 + (size_t)(h * 32 + b) * 16 + m];
  }
  ws[WS_S1 + tid] = a;
  ws[WS_S2 + tid] = c2;
  ws[WS_IS2 + tid] = 1.0f / c2;
}

// ---------------- Kernel D: o2 epilogue ----------------
__global__ __launch_bounds__(256) void epilogue_kernel(const float* __restrict__ ws,
                                                       float* __restrict__ out) {
  int tid = blockIdx.x * 256 + threadIdx.x;  // 0..65535
  int mm = tid >> 12, j = tid & 4095;
  int h = j >> 7, d = j & 127;
  float acc = 0.f;
  #pragma unroll
  for (int b = 0; b < 32; b++)
    acc += ws[WS_PO + (size_t)(h * 32 + b) * 2048 + mm * 128 + d];
  out[tid] = acc / ws[WS_S1 + h * 16 + mm];
}

// ---------------- Kernel C2: c_out (contiguous e2t reads) ----------------
__global__ __launch_bounds__(256) void cout_kernel(const float* __restrict__ ws,
                                                   float* __restrict__ out) {
  int tid = blockIdx.x * 256 + threadIdx.x;
  if (tid >= H_ * PM_) return;
  int h = tid / PM_, p = tid - h * PM_;
  const float4* e2p = (const float4*)(ws + WS_E2 + ((size_t)h * PM_ + p) * 16);
  const float* is2 = ws + WS_IS2 + h * 16;
  float acc = 0.f;
  #pragma unroll
  for (int q = 0; q < 4; q++) {
    float4 v = e2p[q];
    acc += v.x * is2[q * 4] + v.y * is2[q * 4 + 1] + v.z * is2[q * 4 + 2] + v.w * is2[q * 4 + 3];
  }
  out[65536 + tid] = acc;
}

extern "C" void kernel_launch(void* const* d_in, const int* in_sizes, int n_in,
                              void* d_out, int out_size, void* d_ws, size_t ws_size,
                              hipStream_t stream) {
  const float* X     = (const float*)d_in[0];
  const float* Wq    = (const float*)d_in[1];
  const float* Wk    = (const float*)d_in[2];
  const float* Wv    = (const float*)d_in[3];
  const float* cK    = (const float*)d_in[4];
  const float* cV    = (const float*)d_in[5];
  const float* tau   = (const float*)d_in[6];
  const float* noise = (const float*)d_in[7];
  float* out = (float*)d_out;
  float* ws  = (float*)d_ws;

  rmsnorm_kernel<<<16, 256, 0, stream>>>(X, ws);
  proj_kernel<<<1536, 256, 0, stream>>>(Wq, Wk, Wv, ws + WS_XQ, ws);
  proj_reduce_kernel<<<768, 256, 0, stream>>>(ws);
  qk_kernel<<<1024, 256, 0, stream>>>(cK, noise, tau, ws);
  sums_kernel<<<2, 256, 0, stream>>>(ws);
  pv_kernel<<<1024, 256, 0, stream>>>(cV, ws, ws);
  epilogue_kernel<<<256, 256, 0, stream>>>(ws, out);
  cout_kernel<<<1026, 256, 0, stream>>>(ws, out);
}